// Round 1
// baseline (823.607 us; speedup 1.0000x reference)
//
#include <hip/hip_runtime.h>

// IPA forward, MI355X. B=2,N=512,C_S=384,C_Z=128,H=12,D=16,PQ=4,PV=8,OUT_IN=2112.
// R0: correctness-first structure: proj -> fused attention (MFMA bias/out_pair) -> bf16 MFMA output GEMM.

typedef __attribute__((ext_vector_type(8))) short bf16x8;
typedef __attribute__((ext_vector_type(4))) float f32x4;

__device__ __forceinline__ unsigned short f2b(float f) {
  union { float f; unsigned int u; } x; x.f = f;
  unsigned int r = (x.u + 0x7FFFu + ((x.u >> 16) & 1u)) >> 16;
  return (unsigned short)r;
}

// ---------------- K0: wout (2112x384 f32) -> woutT (384x2112 bf16) ----------------
__global__ __launch_bounds__(256) void k_woutT(const float* __restrict__ wout,
                                               unsigned short* __restrict__ woutT) {
  __shared__ float tile[32][33];
  int kb = blockIdx.x * 32, cb = blockIdx.y * 32;
  int tx = threadIdx.x & 31, ty = threadIdx.x >> 5;
  #pragma unroll
  for (int r = ty; r < 32; r += 8) tile[r][tx] = wout[(size_t)(kb + r) * 384 + cb + tx];
  __syncthreads();
  #pragma unroll
  for (int r = ty; r < 32; r += 8) woutT[(size_t)(cb + r) * 2112 + kb + tx] = f2b(tile[tx][r]);
}

// ---------------- K1: projections + global-frame points ----------------
// outputs per row (1152): [0,192) q | [192,576) kv | [576,720) qp raw | [720,1152) kvp raw
__global__ __launch_bounds__(256) void k_proj(
    const float* __restrict__ s,
    const float* __restrict__ wq, const float* __restrict__ bq,
    const float* __restrict__ wkv, const float* __restrict__ bkv,
    const float* __restrict__ wqp, const float* __restrict__ bqp,
    const float* __restrict__ wkvp, const float* __restrict__ bkvp,
    const float* __restrict__ rot, const float* __restrict__ trn,
    float* __restrict__ qws, float* __restrict__ kws, float* __restrict__ vws,
    float* __restrict__ qgws, float* __restrict__ kgws, float* __restrict__ vgws) {
  __shared__ float s_lds[4 * 384];
  __shared__ float praw[4][576];
  int tid = threadIdx.x;
  int row0 = blockIdx.x * 4;

  for (int idx = tid; idx < 1536; idx += 256)
    s_lds[idx] = s[(size_t)row0 * 384 + idx];
  __syncthreads();

  // column assignment
  int no = 0;
  const float* wpt[5]; int stv[5]; float acc[5][4];
  int ocol[5];
  for (int o = tid; o < 1152; o += 256) {
    const float* w; float bias; int ncol, col;
    if (o < 192)      { w = wq;   ncol = 192; col = o;       bias = bq[col]; }
    else if (o < 576) { w = wkv;  ncol = 384; col = o - 192; bias = bkv[col]; }
    else if (o < 720) { w = wqp;  ncol = 144; col = o - 576; bias = bqp[col]; }
    else              { w = wkvp; ncol = 432; col = o - 720; bias = bkvp[col]; }
    wpt[no] = w + col; stv[no] = ncol; ocol[no] = o;
    acc[no][0] = bias; acc[no][1] = bias; acc[no][2] = bias; acc[no][3] = bias;
    no++;
  }

  for (int kc = 0; kc < 384; kc += 8) {
    float sreg[4][8];
    #pragma unroll
    for (int r = 0; r < 4; r++) {
      float4 a = *(const float4*)&s_lds[r * 384 + kc];
      float4 b = *(const float4*)&s_lds[r * 384 + kc + 4];
      sreg[r][0] = a.x; sreg[r][1] = a.y; sreg[r][2] = a.z; sreg[r][3] = a.w;
      sreg[r][4] = b.x; sreg[r][5] = b.y; sreg[r][6] = b.z; sreg[r][7] = b.w;
    }
    for (int oi = 0; oi < no; oi++) {
      const float* wcp = wpt[oi]; int st = stv[oi];
      #pragma unroll
      for (int e = 0; e < 8; e++) {
        float wv = wcp[(size_t)(kc + e) * st];
        #pragma unroll
        for (int r = 0; r < 4; r++) acc[oi][r] += sreg[r][e] * wv;
      }
    }
  }

  for (int oi = 0; oi < no; oi++) {
    int o = ocol[oi];
    #pragma unroll
    for (int r = 0; r < 4; r++) {
      float v = acc[oi][r];
      int bi = row0 + r;
      if (o < 192) qws[(size_t)bi * 192 + o] = v;
      else if (o < 576) {
        int c = o - 192, h = c >> 5, e = c & 31;
        if (e < 16) kws[(size_t)bi * 192 + h * 16 + e] = v;
        else        vws[(size_t)bi * 192 + h * 16 + (e - 16)] = v;
      } else praw[r][o - 576] = v;
    }
  }
  __syncthreads();

  // point transforms: per row 192 points (48 qp + 144 kvp)
  for (int idx = tid; idx < 768; idx += 256) {
    int r = idx / 192, p = idx % 192;
    int bi = row0 + r;
    const float* Rm = rot + (size_t)bi * 9;
    const float* tv = trn + (size_t)bi * 3;
    float x, y, z;
    if (p < 48) { x = praw[r][p]; y = praw[r][48 + p]; z = praw[r][96 + p]; }
    else { int q = p - 48; x = praw[r][144 + q]; y = praw[r][288 + q]; z = praw[r][432 + q]; }
    float gx = Rm[0] * x + Rm[1] * y + Rm[2] * z + tv[0];
    float gy = Rm[3] * x + Rm[4] * y + Rm[5] * z + tv[1];
    float gz = Rm[6] * x + Rm[7] * y + Rm[8] * z + tv[2];
    if (p < 48) {
      float* dst = qgws + (size_t)bi * 144 + p * 3;
      dst[0] = gx; dst[1] = gy; dst[2] = gz;
    } else {
      int q12 = p - 48; int h = q12 / 12, qq = q12 % 12;
      if (qq < 4) {
        float* dst = kgws + (size_t)bi * 144 + (h * 4 + qq) * 3;
        dst[0] = gx; dst[1] = gy; dst[2] = gz;
      } else {
        float* dst = vgws + (size_t)bi * 288 + (h * 8 + (qq - 4)) * 3;
        dst[0] = gx; dst[1] = gy; dst[2] = gz;
      }
    }
  }
}

// ---------------- K2: fused attention per (b,i) ----------------
__global__ __launch_bounds__(512) void k_attn(
    const float* __restrict__ z, const float* __restrict__ mrow,
    const float* __restrict__ rot, const float* __restrict__ trn,
    const float* __restrict__ hwt, const float* __restrict__ wb, const float* __restrict__ bb,
    const float* __restrict__ qws, const float* __restrict__ kws, const float* __restrict__ vws,
    const float* __restrict__ qgws, const float* __restrict__ kgws, const float* __restrict__ vgws,
    unsigned short* __restrict__ feats) {
  __shared__ float logits[16][512];         // 32 KB
  __shared__ unsigned short attnb[8192];    // 16 KB, swizzled [16][512] bf16
  __shared__ unsigned short wbT[16][128];   // 4 KB
  __shared__ float q_lds[192], qg_lds[144], rpg_lds[288];
  __shared__ float rinv[12], hwc[12], Rl[9], tl[3], bbl[16];
  __shared__ float m_i_sh;

  int tid = threadIdx.x;
  int bi = blockIdx.x;
  int b = bi >> 9;
  const float* zbase = z + (size_t)bi * 512 * 128;

  // phase 0: stage per-i data
  if (tid < 192) q_lds[tid] = qws[(size_t)bi * 192 + tid];
  else if (tid < 336) qg_lds[tid - 192] = qgws[(size_t)bi * 144 + (tid - 192)];
  else if (tid < 348) {
    int h = tid - 336; float w = hwt[h];
    hwc[h] = 0.5f * logf(1.0f + __expf(w)) * 0.13608276348795434f; // 0.5*softplus*sqrt(1/54)
  }
  else if (tid >= 352 && tid < 361) Rl[tid - 352] = rot[(size_t)bi * 9 + (tid - 352)];
  else if (tid >= 364 && tid < 367) tl[tid - 364] = trn[(size_t)bi * 3 + (tid - 364)];
  else if (tid >= 368 && tid < 384) bbl[tid - 368] = ((tid - 368) < 12) ? bb[tid - 368] : 0.0f;
  else if (tid == 384) m_i_sh = mrow[bi];
  for (int idx = tid; idx < 2048; idx += 512) {
    int h = idx >> 7, c = idx & 127;
    wbT[h][c] = (h < 12) ? f2b(wb[c * 12 + h]) : (unsigned short)0;
  }
  __syncthreads();

  // phase 1: bias MFMA. logits[h][j] = sqrt(1/3)*(z_row . wb_col + bb)
  {
    int wv = tid >> 6, l = tid & 63, lr = l & 15, lk = l >> 4;
    bf16x8 bfrag[4];
    #pragma unroll
    for (int kc = 0; kc < 4; kc++)
      bfrag[kc] = *(const bf16x8*)&wbT[lr][kc * 32 + lk * 8];
    for (int jt = wv; jt < 32; jt += 8) {
      f32x4 acc = {0.f, 0.f, 0.f, 0.f};
      const float4* z4 = (const float4*)(zbase + (size_t)(jt * 16 + lr) * 128);
      #pragma unroll
      for (int kc = 0; kc < 4; kc++) {
        float4 a0 = z4[kc * 8 + lk * 2 + 0];
        float4 a1 = z4[kc * 8 + lk * 2 + 1];
        bf16x8 afrag;
        afrag[0] = (short)f2b(a0.x); afrag[1] = (short)f2b(a0.y);
        afrag[2] = (short)f2b(a0.z); afrag[3] = (short)f2b(a0.w);
        afrag[4] = (short)f2b(a1.x); afrag[5] = (short)f2b(a1.y);
        afrag[6] = (short)f2b(a1.z); afrag[7] = (short)f2b(a1.w);
        acc = __builtin_amdgcn_mfma_f32_16x16x32_bf16(afrag, bfrag[kc], acc, 0, 0, 0);
      }
      #pragma unroll
      for (int reg = 0; reg < 4; reg++) {
        int j = jt * 16 + lk * 4 + reg;
        logits[lr][j] = 0.5773502691896258f * (acc[reg] + bbl[lr]);
      }
    }
  }
  __syncthreads();

  // phase 2: += qk*sqrt(1/48) - 0.5*hw*pa + mask. one thread per j.
  {
    int j = tid;
    const float* krow = kws + ((size_t)b * 512 + j) * 192;
    const float* kgrow = kgws + ((size_t)b * 512 + j) * 144;
    float mj = mrow[b * 512 + j];
    float mterm = 100000.0f * (m_i_sh * mj - 1.0f);
    #pragma unroll 1
    for (int h = 0; h < 12; h++) {
      float qk = 0.f;
      #pragma unroll
      for (int d = 0; d < 16; d++) qk += q_lds[h * 16 + d] * krow[h * 16 + d];
      float pa = 0.f;
      #pragma unroll
      for (int p = 0; p < 4; p++) {
        float dx = qg_lds[h * 12 + p * 3 + 0] - kgrow[h * 12 + p * 3 + 0];
        float dy = qg_lds[h * 12 + p * 3 + 1] - kgrow[h * 12 + p * 3 + 1];
        float dz = qg_lds[h * 12 + p * 3 + 2] - kgrow[h * 12 + p * 3 + 2];
        pa += dx * dx + dy * dy + dz * dz;
      }
      logits[h][j] += qk * 0.14433756729740643f - hwc[h] * pa + mterm;
    }
  }
  __syncthreads();

  // phase 3: softmax per h (32 lanes per h), store exp back, rinv[h]=1/sum
  if (tid < 384) {
    int h = tid >> 5, g = tid & 31;
    float4 vals[4];
    float mx = -1e30f;
    #pragma unroll
    for (int it = 0; it < 4; it++) {
      vals[it] = *(const float4*)&logits[h][it * 128 + g * 4];
      mx = fmaxf(mx, fmaxf(fmaxf(vals[it].x, vals[it].y), fmaxf(vals[it].z, vals[it].w)));
    }
    #pragma unroll
    for (int off = 16; off > 0; off >>= 1) mx = fmaxf(mx, __shfl_xor(mx, off, 32));
    float sum = 0.f;
    #pragma unroll
    for (int it = 0; it < 4; it++) {
      float4 e;
      e.x = __expf(vals[it].x - mx); e.y = __expf(vals[it].y - mx);
      e.z = __expf(vals[it].z - mx); e.w = __expf(vals[it].w - mx);
      sum += e.x + e.y + e.z + e.w;
      *(float4*)&logits[h][it * 128 + g * 4] = e;
    }
    #pragma unroll
    for (int off = 16; off > 0; off >>= 1) sum += __shfl_xor(sum, off, 32);
    if (g == 0) rinv[h] = 1.0f / sum;
  }
  __syncthreads();

  // phase 4: attnb[h][j] = bf16(p * rinv), swizzled; rows 12..15 zero
  for (int idx = tid; idx < 2048; idx += 512) {
    int h = idx >> 7, jj = idx & 127, j4 = jj * 4;
    ushort4 ob;
    if (h < 12) {
      float4 p4 = *(const float4*)&logits[h][j4];
      float r = rinv[h];
      ob.x = f2b(p4.x * r); ob.y = f2b(p4.y * r);
      ob.z = f2b(p4.z * r); ob.w = f2b(p4.w * r);
    } else { ob.x = ob.y = ob.z = ob.w = 0; }
    int byte = (h * 1024 + j4 * 2) ^ ((h & 7) << 4);
    *(ushort4*)((char*)attnb + byte) = ob;
  }
  __syncthreads();

  size_t fb = (size_t)bi * 2112;

  // phase 5a: out_pair = attn @ z via MFMA; wave -> 16-col slice of C_Z
  {
    int wv = tid >> 6, l = tid & 63, lr = l & 15, lk = l >> 4;
    int c0 = wv * 16;
    f32x4 acc = {0.f, 0.f, 0.f, 0.f};
    const float* zcol = zbase + c0 + lr;
    #pragma unroll
    for (int kc = 0; kc < 16; kc++) {
      int jb = kc * 32 + lk * 8;
      int abyte = (lr * 1024 + jb * 2) ^ ((lr & 7) << 4);
      bf16x8 afrag = *(const bf16x8*)((const char*)attnb + abyte);
      bf16x8 bfrag;
      #pragma unroll
      for (int e = 0; e < 8; e++) bfrag[e] = (short)f2b(zcol[(size_t)(jb + e) * 128]);
      acc = __builtin_amdgcn_mfma_f32_16x16x32_bf16(afrag, bfrag, acc, 0, 0, 0);
    }
    #pragma unroll
    for (int reg = 0; reg < 4; reg++) {
      int h = lk * 4 + reg;
      if (h < 12) feats[fb + 576 + h * 128 + c0 + lr] = f2b(acc[reg]);
    }
  }

  // phase 5b: out_scalar (192) and rpg (288) GEMVs over unnormalized p
  if (tid < 480) {
    float acc = 0.f;
    if (tid < 192) {
      int h = tid >> 4;
      const float* vcol = vws + (size_t)b * 512 * 192 + tid;
      const float* prow = &logits[h][0];
      #pragma unroll 4
      for (int j = 0; j < 512; j++) acc += prow[j] * vcol[(size_t)j * 192];
      feats[fb + tid] = f2b(acc * rinv[h]);
    } else {
      int r = tid - 192; int h = r / 24, rem = r % 24;
      const float* gcol = vgws + (size_t)b * 512 * 288 + h * 24 + rem;
      const float* prow = &logits[h][0];
      #pragma unroll 4
      for (int j = 0; j < 512; j++) acc += prow[j] * gcol[(size_t)j * 288];
      rpg_lds[r] = acc * rinv[h];
    }
  }
  __syncthreads();

  // phase 6: rpl = R^T (rpg - t), norms
  if (tid < 96) {
    int h = tid >> 3, pv = tid & 7;
    float gx = rpg_lds[h * 24 + pv * 3 + 0] - tl[0];
    float gy = rpg_lds[h * 24 + pv * 3 + 1] - tl[1];
    float gz = rpg_lds[h * 24 + pv * 3 + 2] - tl[2];
    float lx = Rl[0] * gx + Rl[3] * gy + Rl[6] * gz;
    float ly = Rl[1] * gx + Rl[4] * gy + Rl[7] * gz;
    float lz = Rl[2] * gx + Rl[5] * gy + Rl[8] * gz;
    feats[fb + 192 + tid] = f2b(lx);
    feats[fb + 288 + tid] = f2b(ly);
    feats[fb + 384 + tid] = f2b(lz);
    feats[fb + 480 + tid] = f2b(sqrtf(lx * lx + ly * ly + lz * lz + 1e-8f));
  }
}

// ---------------- K3: out = (feats @ wout + bout) * mask ----------------
__global__ __launch_bounds__(256) void k_out(const unsigned short* __restrict__ feats,
                                             const unsigned short* __restrict__ woutT,
                                             const float* __restrict__ bout,
                                             const float* __restrict__ mrow,
                                             float* __restrict__ out) {
  __shared__ unsigned short At[2048]; // [64 m][32 k] bf16 swizzled
  __shared__ unsigned short Bt[2048]; // [64 n][32 k] bf16 swizzled
  int m0 = blockIdx.x * 64, n0 = blockIdx.y * 64;
  int tid = threadIdx.x;
  int wv = tid >> 6, l = tid & 63, lr = l & 15, lk = l >> 4;
  int wm = wv >> 1, wn = wv & 1;
  f32x4 acc[2][2] = {};
  int sr = tid >> 2, sq = tid & 3;
  const char* fbase = (const char*)feats + (size_t)(m0 + sr) * 4224 + sq * 16;
  const char* bbase = (const char*)woutT + (size_t)(n0 + sr) * 4224 + sq * 16;
  int sw = ((sr * 64 + sq * 16) ^ ((sr & 7) << 4));

  for (int k0 = 0; k0 < 2112; k0 += 32) {
    uint4 av = *(const uint4*)(fbase + (size_t)k0 * 2);
    uint4 bv = *(const uint4*)(bbase + (size_t)k0 * 2);
    __syncthreads();
    *(uint4*)((char*)At + sw) = av;
    *(uint4*)((char*)Bt + sw) = bv;
    __syncthreads();
    bf16x8 af[2], bf[2];
    #pragma unroll
    for (int mt = 0; mt < 2; mt++) {
      int row = wm * 32 + mt * 16 + lr;
      af[mt] = *(const bf16x8*)((const char*)At + ((row * 64 + lk * 16) ^ ((row & 7) << 4)));
    }
    #pragma unroll
    for (int nt = 0; nt < 2; nt++) {
      int row = wn * 32 + nt * 16 + lr;
      bf[nt] = *(const bf16x8*)((const char*)Bt + ((row * 64 + lk * 16) ^ ((row & 7) << 4)));
    }
    #pragma unroll
    for (int mt = 0; mt < 2; mt++)
      #pragma unroll
      for (int nt = 0; nt < 2; nt++)
        acc[mt][nt] = __builtin_amdgcn_mfma_f32_16x16x32_bf16(af[mt], bf[nt], acc[mt][nt], 0, 0, 0);
  }

  #pragma unroll
  for (int mt = 0; mt < 2; mt++) {
    #pragma unroll
    for (int nt = 0; nt < 2; nt++) {
      int nc = n0 + wn * 32 + nt * 16 + lr;
      float bo = bout[nc];
      #pragma unroll
      for (int reg = 0; reg < 4; reg++) {
        int rowg = m0 + wm * 32 + mt * 16 + lk * 4 + reg;
        out[(size_t)rowg * 384 + nc] = (acc[mt][nt][reg] + bo) * mrow[rowg];
      }
    }
  }
}

extern "C" void kernel_launch(void* const* d_in, const int* in_sizes, int n_in,
                              void* d_out, int out_size, void* d_ws, size_t ws_size,
                              hipStream_t stream) {
  const float* s    = (const float*)d_in[0];
  const float* z    = (const float*)d_in[1];
  const float* rot  = (const float*)d_in[2];
  const float* trn  = (const float*)d_in[3];
  const float* msk  = (const float*)d_in[4];
  const float* wq   = (const float*)d_in[5];
  const float* bq   = (const float*)d_in[6];
  const float* wkv  = (const float*)d_in[7];
  const float* bkv  = (const float*)d_in[8];
  const float* wqp  = (const float*)d_in[9];
  const float* bqp  = (const float*)d_in[10];
  const float* wkvp = (const float*)d_in[11];
  const float* bkvp = (const float*)d_in[12];
  const float* wb   = (const float*)d_in[13];
  const float* bb   = (const float*)d_in[14];
  const float* wout = (const float*)d_in[15];
  const float* bout = (const float*)d_in[16];
  const float* hwt  = (const float*)d_in[17];

  float* qws  = (float*)d_ws;
  float* kws  = qws + 196608;
  float* vws  = kws + 196608;
  float* qgws = vws + 196608;
  float* kgws = qgws + 147456;
  float* vgws = kgws + 147456;
  unsigned short* feats = (unsigned short*)(vgws + 294912);
  unsigned short* woutT = feats + 2162688;
  float* out = (float*)d_out;

  k_woutT<<<dim3(66, 12), dim3(256), 0, stream>>>(wout, woutT);
  k_proj<<<dim3(256), dim3(256), 0, stream>>>(s, wq, bq, wkv, bkv, wqp, bqp, wkvp, bkvp,
                                              rot, trn, qws, kws, vws, qgws, kgws, vgws);
  k_attn<<<dim3(1024), dim3(512), 0, stream>>>(z, msk, rot, trn, hwt, wb, bb,
                                               qws, kws, vws, qgws, kgws, vgws, feats);
  k_out<<<dim3(16, 6), dim3(256), 0, stream>>>(feats, woutT, bout, msk, out);
}

// Round 2
// 423.561 us; speedup vs baseline: 1.9445x; 1.9445x over previous
//
#include <hip/hip_runtime.h>

// IPA forward, MI355X. B=2,N=512,C_S=384,C_Z=128,H=12,D=16,PQ=4,PV=8,OUT_IN=2112.
// R1: coalesced transposed k/kg/v layouts, MFMA for out_scalar/rpg, LDS-staged z for out_pair.

typedef __attribute__((ext_vector_type(8))) short bf16x8;
typedef __attribute__((ext_vector_type(4))) float f32x4;

__device__ __forceinline__ unsigned short f2b(float f) {
  union { float f; unsigned int u; } x; x.f = f;
  unsigned int r = (x.u + 0x7FFFu + ((x.u >> 16) & 1u)) >> 16;
  return (unsigned short)r;
}

// ---------------- K0: wout (2112x384 f32) -> woutT (384x2112 bf16) ----------------
__global__ __launch_bounds__(256) void k_woutT(const float* __restrict__ wout,
                                               unsigned short* __restrict__ woutT) {
  __shared__ float tile[32][33];
  int kb = blockIdx.x * 32, cb = blockIdx.y * 32;
  int tx = threadIdx.x & 31, ty = threadIdx.x >> 5;
  #pragma unroll
  for (int r = ty; r < 32; r += 8) tile[r][tx] = wout[(size_t)(kb + r) * 384 + cb + tx];
  __syncthreads();
  #pragma unroll
  for (int r = ty; r < 32; r += 8) woutT[(size_t)(cb + r) * 2112 + kb + tx] = f2b(tile[tx][r]);
}

// ---------------- K1: projections + global-frame points (transposed outputs) ----------------
// qws [b*i][192] f32, qgws [b*i][144] f32 (per-i),
// kT [b][192][512] f32, kgT [b][144][512] f32, vT [b][480][512] bf16 (cols: 0..191 v(h*16+d), 192..479 vg(h*24+pv*3+c))
__global__ __launch_bounds__(256) void k_proj(
    const float* __restrict__ s,
    const float* __restrict__ wq, const float* __restrict__ bq,
    const float* __restrict__ wkv, const float* __restrict__ bkv,
    const float* __restrict__ wqp, const float* __restrict__ bqp,
    const float* __restrict__ wkvp, const float* __restrict__ bkvp,
    const float* __restrict__ rot, const float* __restrict__ trn,
    float* __restrict__ qws, float* __restrict__ qgws,
    float* __restrict__ kT, float* __restrict__ kgT,
    unsigned short* __restrict__ vT) {
  __shared__ float s_lds[4 * 384];
  __shared__ float praw[4][576];
  int tid = threadIdx.x;
  int row0 = blockIdx.x * 4;

  for (int idx = tid; idx < 1536; idx += 256)
    s_lds[idx] = s[(size_t)row0 * 384 + idx];
  __syncthreads();

  int no = 0;
  const float* wpt[5]; int stv[5]; float acc[5][4];
  int ocol[5];
  for (int o = tid; o < 1152; o += 256) {
    const float* w; float bias; int ncol, col;
    if (o < 192)      { w = wq;   ncol = 192; col = o;       bias = bq[col]; }
    else if (o < 576) { w = wkv;  ncol = 384; col = o - 192; bias = bkv[col]; }
    else if (o < 720) { w = wqp;  ncol = 144; col = o - 576; bias = bqp[col]; }
    else              { w = wkvp; ncol = 432; col = o - 720; bias = bkvp[col]; }
    wpt[no] = w + col; stv[no] = ncol; ocol[no] = o;
    acc[no][0] = bias; acc[no][1] = bias; acc[no][2] = bias; acc[no][3] = bias;
    no++;
  }

  for (int kc = 0; kc < 384; kc += 8) {
    float sreg[4][8];
    #pragma unroll
    for (int r = 0; r < 4; r++) {
      float4 a = *(const float4*)&s_lds[r * 384 + kc];
      float4 b = *(const float4*)&s_lds[r * 384 + kc + 4];
      sreg[r][0] = a.x; sreg[r][1] = a.y; sreg[r][2] = a.z; sreg[r][3] = a.w;
      sreg[r][4] = b.x; sreg[r][5] = b.y; sreg[r][6] = b.z; sreg[r][7] = b.w;
    }
    for (int oi = 0; oi < no; oi++) {
      const float* wcp = wpt[oi]; int st = stv[oi];
      #pragma unroll
      for (int e = 0; e < 8; e++) {
        float wv = wcp[(size_t)(kc + e) * st];
        #pragma unroll
        for (int r = 0; r < 4; r++) acc[oi][r] += sreg[r][e] * wv;
      }
    }
  }

  for (int oi = 0; oi < no; oi++) {
    int o = ocol[oi];
    #pragma unroll
    for (int r = 0; r < 4; r++) {
      float v = acc[oi][r];
      int bi = row0 + r;
      int bb2 = bi >> 9, jj = bi & 511;
      if (o < 192) qws[(size_t)bi * 192 + o] = v;
      else if (o < 576) {
        int c = o - 192, h = c >> 5, e = c & 31;
        if (e < 16) kT[((size_t)bb2 * 192 + h * 16 + e) * 512 + jj] = v;
        else        vT[((size_t)bb2 * 480 + h * 16 + (e - 16)) * 512 + jj] = f2b(v);
      } else praw[r][o - 576] = v;
    }
  }
  __syncthreads();

  // point transforms: per row 192 points (48 qp + 144 kvp)
  for (int idx = tid; idx < 768; idx += 256) {
    int r = idx / 192, p = idx % 192;
    int bi = row0 + r;
    int bb2 = bi >> 9, jj = bi & 511;
    const float* Rm = rot + (size_t)bi * 9;
    const float* tv = trn + (size_t)bi * 3;
    float x, y, z;
    if (p < 48) { x = praw[r][p]; y = praw[r][48 + p]; z = praw[r][96 + p]; }
    else { int q = p - 48; x = praw[r][144 + q]; y = praw[r][288 + q]; z = praw[r][432 + q]; }
    float gx = Rm[0] * x + Rm[1] * y + Rm[2] * z + tv[0];
    float gy = Rm[3] * x + Rm[4] * y + Rm[5] * z + tv[1];
    float gz = Rm[6] * x + Rm[7] * y + Rm[8] * z + tv[2];
    if (p < 48) {
      float* dst = qgws + (size_t)bi * 144 + p * 3;
      dst[0] = gx; dst[1] = gy; dst[2] = gz;
    } else {
      int q12 = p - 48; int h = q12 / 12, qq = q12 % 12;
      if (qq < 4) {
        size_t base = ((size_t)bb2 * 144 + h * 12 + qq * 3) * 512 + jj;
        kgT[base] = gx; kgT[base + 512] = gy; kgT[base + 1024] = gz;
      } else {
        size_t base = ((size_t)bb2 * 480 + 192 + h * 24 + (qq - 4) * 3) * 512 + jj;
        vT[base] = f2b(gx); vT[base + 512] = f2b(gy); vT[base + 1024] = f2b(gz);
      }
    }
  }
}

// ---------------- K2: fused attention per (b,i) ----------------
__global__ __launch_bounds__(512, 6) void k_attn(
    const float* __restrict__ z, const float* __restrict__ mrow,
    const float* __restrict__ rot, const float* __restrict__ trn,
    const float* __restrict__ hwt, const float* __restrict__ wb, const float* __restrict__ bb,
    const float* __restrict__ qws, const float* __restrict__ qgws,
    const float* __restrict__ kT, const float* __restrict__ kgT,
    const unsigned short* __restrict__ vT,
    unsigned short* __restrict__ feats) {
  __shared__ float logits[12][512];          // 24KB; reused as z-stage in phase 5a
  __shared__ unsigned short attnb[8192];     // 16KB, swizzled [16][512] bf16 (rows 12-15 zero)
  __shared__ unsigned short wbT[16][128];    // 4KB
  __shared__ float q_lds[192], qg_lds[144], rpg_lds[288];
  __shared__ float rinv[12], hwc[12], Rl[9], tl[3], bbl[16];
  __shared__ float m_i_sh;

  int tid = threadIdx.x;
  int bi = blockIdx.x;
  int b = bi >> 9;
  const float* zbase = z + (size_t)bi * 512 * 128;
  int wv = tid >> 6, l = tid & 63, lr = l & 15, lk = l >> 4;

  // phase 0: stage per-i data
  if (tid < 192) q_lds[tid] = qws[(size_t)bi * 192 + tid];
  else if (tid < 336) qg_lds[tid - 192] = qgws[(size_t)bi * 144 + (tid - 192)];
  else if (tid < 348) {
    int h = tid - 336; float w = hwt[h];
    hwc[h] = 0.5f * logf(1.0f + __expf(w)) * 0.13608276348795434f; // 0.5*softplus*sqrt(1/54)
  }
  else if (tid >= 352 && tid < 361) Rl[tid - 352] = rot[(size_t)bi * 9 + (tid - 352)];
  else if (tid >= 364 && tid < 367) tl[tid - 364] = trn[(size_t)bi * 3 + (tid - 364)];
  else if (tid >= 368 && tid < 384) bbl[tid - 368] = ((tid - 368) < 12) ? bb[tid - 368] : 0.0f;
  else if (tid == 384) m_i_sh = mrow[bi];
  for (int idx = tid; idx < 2048; idx += 512) {
    int h = idx >> 7, c = idx & 127;
    wbT[h][c] = (h < 12) ? f2b(wb[c * 12 + h]) : (unsigned short)0;
  }
  __syncthreads();

  // phase 1: bias MFMA. logits[h][j] = sqrt(1/3)*(z_row . wb_col + bb)
  {
    bf16x8 bfrag[4];
    #pragma unroll
    for (int kc = 0; kc < 4; kc++)
      bfrag[kc] = *(const bf16x8*)&wbT[lr][kc * 32 + lk * 8];
    for (int jt = wv; jt < 32; jt += 8) {
      f32x4 acc = {0.f, 0.f, 0.f, 0.f};
      const float4* z4 = (const float4*)(zbase + (size_t)(jt * 16 + lr) * 128);
      #pragma unroll
      for (int kc = 0; kc < 4; kc++) {
        float4 a0 = z4[kc * 8 + lk * 2 + 0];
        float4 a1 = z4[kc * 8 + lk * 2 + 1];
        bf16x8 afrag;
        afrag[0] = (short)f2b(a0.x); afrag[1] = (short)f2b(a0.y);
        afrag[2] = (short)f2b(a0.z); afrag[3] = (short)f2b(a0.w);
        afrag[4] = (short)f2b(a1.x); afrag[5] = (short)f2b(a1.y);
        afrag[6] = (short)f2b(a1.z); afrag[7] = (short)f2b(a1.w);
        acc = __builtin_amdgcn_mfma_f32_16x16x32_bf16(afrag, bfrag[kc], acc, 0, 0, 0);
      }
      if (lr < 12) {
        #pragma unroll
        for (int reg = 0; reg < 4; reg++) {
          int j = jt * 16 + lk * 4 + reg;
          logits[lr][j] = 0.5773502691896258f * (acc[reg] + bbl[lr]);
        }
      }
    }
  }
  __syncthreads();

  // phase 2: += qk*sqrt(1/48) - 0.5*hw*pa + mask. one thread per j, coalesced transposed reads.
  {
    int j = tid;
    const float* kTb  = kT  + (size_t)b * 192 * 512 + j;
    const float* kgTb = kgT + (size_t)b * 144 * 512 + j;
    float mj = mrow[b * 512 + j];
    float mterm = 100000.0f * (m_i_sh * mj - 1.0f);
    #pragma unroll 2
    for (int h = 0; h < 12; h++) {
      float qk = 0.f;
      #pragma unroll
      for (int d = 0; d < 16; d++) qk += q_lds[h * 16 + d] * kTb[(size_t)(h * 16 + d) * 512];
      float pa = 0.f;
      #pragma unroll
      for (int pc = 0; pc < 12; pc++) {
        float diff = qg_lds[h * 12 + pc] - kgTb[(size_t)(h * 12 + pc) * 512];
        pa += diff * diff;
      }
      logits[h][j] += qk * 0.14433756729740643f - hwc[h] * pa + mterm;
    }
  }
  __syncthreads();

  // phase 3: softmax per h (32 lanes per h), store exp back, rinv[h]=1/sum
  if (tid < 384) {
    int h = tid >> 5, g = tid & 31;
    float4 vals[4];
    float mx = -1e30f;
    #pragma unroll
    for (int it = 0; it < 4; it++) {
      vals[it] = *(const float4*)&logits[h][it * 128 + g * 4];
      mx = fmaxf(mx, fmaxf(fmaxf(vals[it].x, vals[it].y), fmaxf(vals[it].z, vals[it].w)));
    }
    #pragma unroll
    for (int off = 16; off > 0; off >>= 1) mx = fmaxf(mx, __shfl_xor(mx, off, 32));
    float sum = 0.f;
    #pragma unroll
    for (int it = 0; it < 4; it++) {
      float4 e;
      e.x = __expf(vals[it].x - mx); e.y = __expf(vals[it].y - mx);
      e.z = __expf(vals[it].z - mx); e.w = __expf(vals[it].w - mx);
      sum += e.x + e.y + e.z + e.w;
      *(float4*)&logits[h][it * 128 + g * 4] = e;
    }
    #pragma unroll
    for (int off = 16; off > 0; off >>= 1) sum += __shfl_xor(sum, off, 32);
    if (g == 0) rinv[h] = 1.0f / sum;
  }
  __syncthreads();

  // phase 4: attnb[h][j] = bf16(p * rinv), swizzled; rows 12..15 zero
  for (int idx = tid; idx < 2048; idx += 512) {
    int h = idx >> 7, jj = idx & 127, j4 = jj * 4;
    ushort4 ob;
    if (h < 12) {
      float4 p4 = *(const float4*)&logits[h][j4];
      float r = rinv[h];
      ob.x = f2b(p4.x * r); ob.y = f2b(p4.y * r);
      ob.z = f2b(p4.z * r); ob.w = f2b(p4.w * r);
    } else { ob.x = ob.y = ob.z = ob.w = 0; }
    int byte = (h * 1024 + j4 * 2) ^ ((h & 7) << 4);
    *(ushort4*)((char*)attnb + byte) = ob;
  }
  __syncthreads();

  size_t fb = (size_t)bi * 2112;

  // phase 5a: out_pair = attn @ z via MFMA, z staged in LDS (bf16), depth-2 prefetch.
  {
    unsigned short* zs = (unsigned short*)&logits[0][0]; // 2 x 8KB buffers
    int srow = tid >> 4;             // 0..31 (row within 32-row tile)
    int scol = (tid & 15) << 3;      // 0,8,...,120
    const float* zsrc = zbase + srow * 128 + scol;
    int wbyte = (srow * 256 + scol * 2) ^ (((srow + (srow >> 3)) & 3) << 4);
    int c0 = wv * 16;
    f32x4 acc = {0.f, 0.f, 0.f, 0.f};

    float4 ra0 = *(const float4*)(zsrc);
    float4 ra1 = *(const float4*)(zsrc + 4);
    float4 rb0 = *(const float4*)(zsrc + 32 * 128);
    float4 rb1 = *(const float4*)(zsrc + 32 * 128 + 4);

    #pragma unroll 1
    for (int kt = 0; kt < 16; kt += 2) {
      // even tile: regs RA -> buf 0
      {
        bf16x8 zc;
        zc[0] = (short)f2b(ra0.x); zc[1] = (short)f2b(ra0.y);
        zc[2] = (short)f2b(ra0.z); zc[3] = (short)f2b(ra0.w);
        zc[4] = (short)f2b(ra1.x); zc[5] = (short)f2b(ra1.y);
        zc[6] = (short)f2b(ra1.z); zc[7] = (short)f2b(ra1.w);
        *(bf16x8*)((char*)zs + wbyte) = zc;
        if (kt + 2 < 16) {
          ra0 = *(const float4*)(zsrc + (size_t)(kt + 2) * 32 * 128);
          ra1 = *(const float4*)(zsrc + (size_t)(kt + 2) * 32 * 128 + 4);
        }
        __syncthreads();
        int abyte = (lr * 1024 + (kt * 32 + lk * 8) * 2) ^ ((lr & 7) << 4);
        bf16x8 afrag = *(const bf16x8*)((const char*)attnb + abyte);
        bf16x8 bfrag;
        #pragma unroll
        for (int e = 0; e < 8; e++) {
          int row = lk * 8 + e;
          int rbyte = (row * 256 + (c0 + lr) * 2) ^ (((row + (row >> 3)) & 3) << 4);
          bfrag[e] = *(const short*)((const char*)zs + rbyte);
        }
        acc = __builtin_amdgcn_mfma_f32_16x16x32_bf16(afrag, bfrag, acc, 0, 0, 0);
      }
      __syncthreads();
      // odd tile: regs RB -> buf 1
      {
        bf16x8 zc;
        zc[0] = (short)f2b(rb0.x); zc[1] = (short)f2b(rb0.y);
        zc[2] = (short)f2b(rb0.z); zc[3] = (short)f2b(rb0.w);
        zc[4] = (short)f2b(rb1.x); zc[5] = (short)f2b(rb1.y);
        zc[6] = (short)f2b(rb1.z); zc[7] = (short)f2b(rb1.w);
        *(bf16x8*)((char*)zs + 8192 + wbyte) = zc;
        if (kt + 3 < 16) {
          rb0 = *(const float4*)(zsrc + (size_t)(kt + 3) * 32 * 128);
          rb1 = *(const float4*)(zsrc + (size_t)(kt + 3) * 32 * 128 + 4);
        }
        __syncthreads();
        int abyte = (lr * 1024 + ((kt + 1) * 32 + lk * 8) * 2) ^ ((lr & 7) << 4);
        bf16x8 afrag = *(const bf16x8*)((const char*)attnb + abyte);
        bf16x8 bfrag;
        #pragma unroll
        for (int e = 0; e < 8; e++) {
          int row = lk * 8 + e;
          int rbyte = (row * 256 + (c0 + lr) * 2) ^ (((row + (row >> 3)) & 3) << 4);
          bfrag[e] = *(const short*)((const char*)zs + 8192 + rbyte);
        }
        acc = __builtin_amdgcn_mfma_f32_16x16x32_bf16(afrag, bfrag, acc, 0, 0, 0);
      }
      if (kt + 2 < 16) __syncthreads();
    }
    #pragma unroll
    for (int reg = 0; reg < 4; reg++) {
      int h = lk * 4 + reg;
      if (h < 12) feats[fb + 576 + h * 128 + c0 + lr] = f2b(acc[reg]);
    }
  }

  // phase 5b: [out_scalar | rpg] = attn @ [v | vg] via MFMA over vT (L2-resident, contiguous 16B B-frags)
  {
    const unsigned short* vTb = vT + (size_t)b * 480 * 512;
    for (int t = wv; t < 30; t += 8) {
      int c0 = t * 16;
      const unsigned short* vrow = vTb + (size_t)(c0 + lr) * 512 + lk * 8;
      f32x4 acc = {0.f, 0.f, 0.f, 0.f};
      #pragma unroll
      for (int kc = 0; kc < 16; kc++) {
        bf16x8 bfrag = *(const bf16x8*)(vrow + kc * 32);
        int abyte = (lr * 1024 + (kc * 32 + lk * 8) * 2) ^ ((lr & 7) << 4);
        bf16x8 afrag = *(const bf16x8*)((const char*)attnb + abyte);
        acc = __builtin_amdgcn_mfma_f32_16x16x32_bf16(afrag, bfrag, acc, 0, 0, 0);
      }
      #pragma unroll
      for (int reg = 0; reg < 4; reg++) {
        int h = lk * 4 + reg;
        if (h < 12) {
          int c = c0 + lr;
          if (c < 192) { if ((c >> 4) == h) feats[fb + c] = f2b(acc[reg]); }
          else { int r = c - 192; if (r >= h * 24 && r < h * 24 + 24) rpg_lds[r] = acc[reg]; }
        }
      }
    }
  }
  __syncthreads();

  // phase 6: rpl = R^T (rpg - t), norms
  if (tid < 96) {
    int h = tid >> 3, pv = tid & 7;
    float gx = rpg_lds[h * 24 + pv * 3 + 0] - tl[0];
    float gy = rpg_lds[h * 24 + pv * 3 + 1] - tl[1];
    float gz = rpg_lds[h * 24 + pv * 3 + 2] - tl[2];
    float lx = Rl[0] * gx + Rl[3] * gy + Rl[6] * gz;
    float ly = Rl[1] * gx + Rl[4] * gy + Rl[7] * gz;
    float lz = Rl[2] * gx + Rl[5] * gy + Rl[8] * gz;
    feats[fb + 192 + tid] = f2b(lx);
    feats[fb + 288 + tid] = f2b(ly);
    feats[fb + 384 + tid] = f2b(lz);
    feats[fb + 480 + tid] = f2b(sqrtf(lx * lx + ly * ly + lz * lz + 1e-8f));
  }
}

// ---------------- K3: out = (feats @ wout + bout) * mask ----------------
__global__ __launch_bounds__(256) void k_out(const unsigned short* __restrict__ feats,
                                             const unsigned short* __restrict__ woutT,
                                             const float* __restrict__ bout,
                                             const float* __restrict__ mrow,
                                             float* __restrict__ out) {
  __shared__ unsigned short At[2048]; // [64 m][32 k] bf16 swizzled
  __shared__ unsigned short Bt[2048]; // [64 n][32 k] bf16 swizzled
  int m0 = blockIdx.x * 64, n0 = blockIdx.y * 64;
  int tid = threadIdx.x;
  int wv = tid >> 6, l = tid & 63, lr = l & 15, lk = l >> 4;
  int wm = wv >> 1, wn = wv & 1;
  f32x4 acc[2][2] = {};
  int sr = tid >> 2, sq = tid & 3;
  const char* fbase = (const char*)feats + (size_t)(m0 + sr) * 4224 + sq * 16;
  const char* bbase = (const char*)woutT + (size_t)(n0 + sr) * 4224 + sq * 16;
  int sw = ((sr * 64 + sq * 16) ^ ((sr & 7) << 4));

  uint4 av = *(const uint4*)(fbase);
  uint4 bv = *(const uint4*)(bbase);
  for (int k0 = 0; k0 < 2112; k0 += 32) {
    __syncthreads();
    *(uint4*)((char*)At + sw) = av;
    *(uint4*)((char*)Bt + sw) = bv;
    __syncthreads();
    if (k0 + 32 < 2112) {
      av = *(const uint4*)(fbase + (size_t)(k0 + 32) * 2);
      bv = *(const uint4*)(bbase + (size_t)(k0 + 32) * 2);
    }
    bf16x8 af[2], bf[2];
    #pragma unroll
    for (int mt = 0; mt < 2; mt++) {
      int row = wm * 32 + mt * 16 + lr;
      af[mt] = *(const bf16x8*)((const char*)At + ((row * 64 + lk * 16) ^ ((row & 7) << 4)));
    }
    #pragma unroll
    for (int nt = 0; nt < 2; nt++) {
      int row = wn * 32 + nt * 16 + lr;
      bf[nt] = *(const bf16x8*)((const char*)Bt + ((row * 64 + lk * 16) ^ ((row & 7) << 4)));
    }
    #pragma unroll
    for (int mt = 0; mt < 2; mt++)
      #pragma unroll
      for (int nt = 0; nt < 2; nt++)
        acc[mt][nt] = __builtin_amdgcn_mfma_f32_16x16x32_bf16(af[mt], bf[nt], acc[mt][nt], 0, 0, 0);
  }

  #pragma unroll
  for (int mt = 0; mt < 2; mt++) {
    #pragma unroll
    for (int nt = 0; nt < 2; nt++) {
      int nc = n0 + wn * 32 + nt * 16 + lr;
      float bo = bout[nc];
      #pragma unroll
      for (int reg = 0; reg < 4; reg++) {
        int rowg = m0 + wm * 32 + mt * 16 + lk * 4 + reg;
        out[(size_t)rowg * 384 + nc] = (acc[mt][nt][reg] + bo) * mrow[rowg];
      }
    }
  }
}

extern "C" void kernel_launch(void* const* d_in, const int* in_sizes, int n_in,
                              void* d_out, int out_size, void* d_ws, size_t ws_size,
                              hipStream_t stream) {
  const float* s    = (const float*)d_in[0];
  const float* z    = (const float*)d_in[1];
  const float* rot  = (const float*)d_in[2];
  const float* trn  = (const float*)d_in[3];
  const float* msk  = (const float*)d_in[4];
  const float* wq   = (const float*)d_in[5];
  const float* bq   = (const float*)d_in[6];
  const float* wkv  = (const float*)d_in[7];
  const float* bkv  = (const float*)d_in[8];
  const float* wqp  = (const float*)d_in[9];
  const float* bqp  = (const float*)d_in[10];
  const float* wkvp = (const float*)d_in[11];
  const float* bkvp = (const float*)d_in[12];
  const float* wb   = (const float*)d_in[13];
  const float* bb   = (const float*)d_in[14];
  const float* wout = (const float*)d_in[15];
  const float* bout = (const float*)d_in[16];
  const float* hwt  = (const float*)d_in[17];

  float* qws  = (float*)d_ws;                       // 196608 f32
  float* qgws = qws + 196608;                       // 147456 f32
  float* kT   = qgws + 147456;                      // 196608 f32
  float* kgT  = kT + 196608;                        // 147456 f32
  unsigned short* vT    = (unsigned short*)(kgT + 147456);  // 491520 u16
  unsigned short* feats = vT + 491520;              // 2162688 u16
  unsigned short* woutT = feats + 2162688;          // 811008 u16
  float* out = (float*)d_out;

  k_woutT<<<dim3(66, 12), dim3(256), 0, stream>>>(wout, woutT);
  k_proj<<<dim3(256), dim3(256), 0, stream>>>(s, wq, bq, wkv, bkv, wqp, bqp, wkvp, bkvp,
                                              rot, trn, qws, qgws, kT, kgT, vT);
  k_attn<<<dim3(1024), dim3(512), 0, stream>>>(z, msk, rot, trn, hwt, wb, bb,
                                               qws, qgws, kT, kgT, vT, feats);
  k_out<<<dim3(16, 6), dim3(256), 0, stream>>>(feats, woutT, bout, msk, out);
}

// Round 3
// 344.988 us; speedup vs baseline: 2.3874x; 1.2278x over previous
//
#include <hip/hip_runtime.h>

// IPA forward, MI355X. B=2,N=512,C_S=384,C_Z=128,H=12,D=16,PQ=4,PV=8,OUT_IN=2112.
// R2: phase-5a rewritten (LDS-transposed zT tiles, 1 barrier/tile, vector frag reads);
//     k_proj at 512 threads for 2 waves/SIMD.

typedef __attribute__((ext_vector_type(8))) short bf16x8;
typedef __attribute__((ext_vector_type(4))) float f32x4;

__device__ __forceinline__ unsigned short f2b(float f) {
  union { float f; unsigned int u; } x; x.f = f;
  unsigned int r = (x.u + 0x7FFFu + ((x.u >> 16) & 1u)) >> 16;
  return (unsigned short)r;
}

// ---------------- K0: wout (2112x384 f32) -> woutT (384x2112 bf16) ----------------
__global__ __launch_bounds__(256) void k_woutT(const float* __restrict__ wout,
                                               unsigned short* __restrict__ woutT) {
  __shared__ float tile[32][33];
  int kb = blockIdx.x * 32, cb = blockIdx.y * 32;
  int tx = threadIdx.x & 31, ty = threadIdx.x >> 5;
  #pragma unroll
  for (int r = ty; r < 32; r += 8) tile[r][tx] = wout[(size_t)(kb + r) * 384 + cb + tx];
  __syncthreads();
  #pragma unroll
  for (int r = ty; r < 32; r += 8) woutT[(size_t)(cb + r) * 2112 + kb + tx] = f2b(tile[tx][r]);
}

// ---------------- K1: projections + global-frame points (transposed outputs) ----------------
// qws [b*i][192] f32, qgws [b*i][144] f32 (per-i),
// kT [b][192][512] f32, kgT [b][144][512] f32, vT [b][480][512] bf16
__global__ __launch_bounds__(512) void k_proj(
    const float* __restrict__ s,
    const float* __restrict__ wq, const float* __restrict__ bq,
    const float* __restrict__ wkv, const float* __restrict__ bkv,
    const float* __restrict__ wqp, const float* __restrict__ bqp,
    const float* __restrict__ wkvp, const float* __restrict__ bkvp,
    const float* __restrict__ rot, const float* __restrict__ trn,
    float* __restrict__ qws, float* __restrict__ qgws,
    float* __restrict__ kT, float* __restrict__ kgT,
    unsigned short* __restrict__ vT) {
  __shared__ float s_lds[4 * 384];
  __shared__ float praw[4][576];
  int tid = threadIdx.x;
  int row0 = blockIdx.x * 4;

  for (int idx = tid; idx < 1536; idx += 512)
    s_lds[idx] = s[(size_t)row0 * 384 + idx];
  __syncthreads();

  int no = 0;
  const float* wpt[3]; int stv[3]; float acc[3][4];
  int ocol[3];
  for (int o = tid; o < 1152; o += 512) {
    const float* w; float bias; int ncol, col;
    if (o < 192)      { w = wq;   ncol = 192; col = o;       bias = bq[col]; }
    else if (o < 576) { w = wkv;  ncol = 384; col = o - 192; bias = bkv[col]; }
    else if (o < 720) { w = wqp;  ncol = 144; col = o - 576; bias = bqp[col]; }
    else              { w = wkvp; ncol = 432; col = o - 720; bias = bkvp[col]; }
    wpt[no] = w + col; stv[no] = ncol; ocol[no] = o;
    acc[no][0] = bias; acc[no][1] = bias; acc[no][2] = bias; acc[no][3] = bias;
    no++;
  }

  for (int kc = 0; kc < 384; kc += 8) {
    float sreg[4][8];
    #pragma unroll
    for (int r = 0; r < 4; r++) {
      float4 a = *(const float4*)&s_lds[r * 384 + kc];
      float4 b = *(const float4*)&s_lds[r * 384 + kc + 4];
      sreg[r][0] = a.x; sreg[r][1] = a.y; sreg[r][2] = a.z; sreg[r][3] = a.w;
      sreg[r][4] = b.x; sreg[r][5] = b.y; sreg[r][6] = b.z; sreg[r][7] = b.w;
    }
    for (int oi = 0; oi < no; oi++) {
      const float* wcp = wpt[oi]; int st = stv[oi];
      #pragma unroll
      for (int e = 0; e < 8; e++) {
        float wv = wcp[(size_t)(kc + e) * st];
        #pragma unroll
        for (int r = 0; r < 4; r++) acc[oi][r] += sreg[r][e] * wv;
      }
    }
  }

  for (int oi = 0; oi < no; oi++) {
    int o = ocol[oi];
    #pragma unroll
    for (int r = 0; r < 4; r++) {
      float v = acc[oi][r];
      int bi = row0 + r;
      int bb2 = bi >> 9, jj = bi & 511;
      if (o < 192) qws[(size_t)bi * 192 + o] = v;
      else if (o < 576) {
        int c = o - 192, h = c >> 5, e = c & 31;
        if (e < 16) kT[((size_t)bb2 * 192 + h * 16 + e) * 512 + jj] = v;
        else        vT[((size_t)bb2 * 480 + h * 16 + (e - 16)) * 512 + jj] = f2b(v);
      } else praw[r][o - 576] = v;
    }
  }
  __syncthreads();

  // point transforms: per row 192 points (48 qp + 144 kvp)
  for (int idx = tid; idx < 768; idx += 512) {
    int r = idx / 192, p = idx % 192;
    int bi = row0 + r;
    int bb2 = bi >> 9, jj = bi & 511;
    const float* Rm = rot + (size_t)bi * 9;
    const float* tv = trn + (size_t)bi * 3;
    float x, y, z;
    if (p < 48) { x = praw[r][p]; y = praw[r][48 + p]; z = praw[r][96 + p]; }
    else { int q = p - 48; x = praw[r][144 + q]; y = praw[r][288 + q]; z = praw[r][432 + q]; }
    float gx = Rm[0] * x + Rm[1] * y + Rm[2] * z + tv[0];
    float gy = Rm[3] * x + Rm[4] * y + Rm[5] * z + tv[1];
    float gz = Rm[6] * x + Rm[7] * y + Rm[8] * z + tv[2];
    if (p < 48) {
      float* dst = qgws + (size_t)bi * 144 + p * 3;
      dst[0] = gx; dst[1] = gy; dst[2] = gz;
    } else {
      int q12 = p - 48; int h = q12 / 12, qq = q12 % 12;
      if (qq < 4) {
        size_t base = ((size_t)bb2 * 144 + h * 12 + qq * 3) * 512 + jj;
        kgT[base] = gx; kgT[base + 512] = gy; kgT[base + 1024] = gz;
      } else {
        size_t base = ((size_t)bb2 * 480 + 192 + h * 24 + (qq - 4) * 3) * 512 + jj;
        vT[base] = f2b(gx); vT[base + 512] = f2b(gy); vT[base + 1024] = f2b(gz);
      }
    }
  }
}

// ---------------- K2: fused attention per (b,i) ----------------
__global__ __launch_bounds__(512, 6) void k_attn(
    const float* __restrict__ z, const float* __restrict__ mrow,
    const float* __restrict__ rot, const float* __restrict__ trn,
    const float* __restrict__ hwt, const float* __restrict__ wb, const float* __restrict__ bb,
    const float* __restrict__ qws, const float* __restrict__ qgws,
    const float* __restrict__ kT, const float* __restrict__ kgT,
    const unsigned short* __restrict__ vT,
    unsigned short* __restrict__ feats) {
  __shared__ float logits[12][512];          // 24KB; reused as zT-stage (2x10KB) in phase 5a
  __shared__ unsigned short attnb[8192];     // 16KB, swizzled [16][512] bf16 (rows 12-15 zero)
  __shared__ unsigned short wbT[16][128];    // 4KB
  __shared__ float q_lds[192], qg_lds[144], rpg_lds[288];
  __shared__ float rinv[12], hwc[12], Rl[9], tl[3], bbl[16];
  __shared__ float m_i_sh;

  int tid = threadIdx.x;
  int bi = blockIdx.x;
  int b = bi >> 9;
  const float* zbase = z + (size_t)bi * 512 * 128;
  int wv = tid >> 6, l = tid & 63, lr = l & 15, lk = l >> 4;

  // phase 0: stage per-i data
  if (tid < 192) q_lds[tid] = qws[(size_t)bi * 192 + tid];
  else if (tid < 336) qg_lds[tid - 192] = qgws[(size_t)bi * 144 + (tid - 192)];
  else if (tid < 348) {
    int h = tid - 336; float w = hwt[h];
    hwc[h] = 0.5f * logf(1.0f + __expf(w)) * 0.13608276348795434f; // 0.5*softplus*sqrt(1/54)
  }
  else if (tid >= 352 && tid < 361) Rl[tid - 352] = rot[(size_t)bi * 9 + (tid - 352)];
  else if (tid >= 364 && tid < 367) tl[tid - 364] = trn[(size_t)bi * 3 + (tid - 364)];
  else if (tid >= 368 && tid < 384) bbl[tid - 368] = ((tid - 368) < 12) ? bb[tid - 368] : 0.0f;
  else if (tid == 384) m_i_sh = mrow[bi];
  for (int idx = tid; idx < 2048; idx += 512) {
    int h = idx >> 7, c = idx & 127;
    wbT[h][c] = (h < 12) ? f2b(wb[c * 12 + h]) : (unsigned short)0;
  }
  __syncthreads();

  // phase 1: bias MFMA. logits[h][j] = sqrt(1/3)*(z_row . wb_col + bb)
  {
    bf16x8 bfrag[4];
    #pragma unroll
    for (int kc = 0; kc < 4; kc++)
      bfrag[kc] = *(const bf16x8*)&wbT[lr][kc * 32 + lk * 8];
    #pragma unroll 2
    for (int jt = wv; jt < 32; jt += 8) {
      f32x4 acc = {0.f, 0.f, 0.f, 0.f};
      const float4* z4 = (const float4*)(zbase + (size_t)(jt * 16 + lr) * 128);
      #pragma unroll
      for (int kc = 0; kc < 4; kc++) {
        float4 a0 = z4[kc * 8 + lk * 2 + 0];
        float4 a1 = z4[kc * 8 + lk * 2 + 1];
        bf16x8 afrag;
        afrag[0] = (short)f2b(a0.x); afrag[1] = (short)f2b(a0.y);
        afrag[2] = (short)f2b(a0.z); afrag[3] = (short)f2b(a0.w);
        afrag[4] = (short)f2b(a1.x); afrag[5] = (short)f2b(a1.y);
        afrag[6] = (short)f2b(a1.z); afrag[7] = (short)f2b(a1.w);
        acc = __builtin_amdgcn_mfma_f32_16x16x32_bf16(afrag, bfrag[kc], acc, 0, 0, 0);
      }
      if (lr < 12) {
        #pragma unroll
        for (int reg = 0; reg < 4; reg++) {
          int j = jt * 16 + lk * 4 + reg;
          logits[lr][j] = 0.5773502691896258f * (acc[reg] + bbl[lr]);
        }
      }
    }
  }
  __syncthreads();

  // phase 2: += qk*sqrt(1/48) - 0.5*hw*pa + mask. one thread per j, coalesced transposed reads.
  {
    int j = tid;
    const float* kTb  = kT  + (size_t)b * 192 * 512 + j;
    const float* kgTb = kgT + (size_t)b * 144 * 512 + j;
    float mj = mrow[b * 512 + j];
    float mterm = 100000.0f * (m_i_sh * mj - 1.0f);
    #pragma unroll 2
    for (int h = 0; h < 12; h++) {
      float qk = 0.f;
      #pragma unroll
      for (int d = 0; d < 16; d++) qk += q_lds[h * 16 + d] * kTb[(size_t)(h * 16 + d) * 512];
      float pa = 0.f;
      #pragma unroll
      for (int pc = 0; pc < 12; pc++) {
        float diff = qg_lds[h * 12 + pc] - kgTb[(size_t)(h * 12 + pc) * 512];
        pa += diff * diff;
      }
      logits[h][j] += qk * 0.14433756729740643f - hwc[h] * pa + mterm;
    }
  }
  __syncthreads();

  // phase 3: softmax per h (32 lanes per h), store exp back, rinv[h]=1/sum
  if (tid < 384) {
    int h = tid >> 5, g = tid & 31;
    float4 vals[4];
    float mx = -1e30f;
    #pragma unroll
    for (int it = 0; it < 4; it++) {
      vals[it] = *(const float4*)&logits[h][it * 128 + g * 4];
      mx = fmaxf(mx, fmaxf(fmaxf(vals[it].x, vals[it].y), fmaxf(vals[it].z, vals[it].w)));
    }
    #pragma unroll
    for (int off = 16; off > 0; off >>= 1) mx = fmaxf(mx, __shfl_xor(mx, off, 32));
    float sum = 0.f;
    #pragma unroll
    for (int it = 0; it < 4; it++) {
      float4 e;
      e.x = __expf(vals[it].x - mx); e.y = __expf(vals[it].y - mx);
      e.z = __expf(vals[it].z - mx); e.w = __expf(vals[it].w - mx);
      sum += e.x + e.y + e.z + e.w;
      *(float4*)&logits[h][it * 128 + g * 4] = e;
    }
    #pragma unroll
    for (int off = 16; off > 0; off >>= 1) sum += __shfl_xor(sum, off, 32);
    if (g == 0) rinv[h] = 1.0f / sum;
  }
  __syncthreads();

  // phase 4: attnb[h][j] = bf16(p * rinv), swizzled; rows 12..15 zero
  for (int idx = tid; idx < 2048; idx += 512) {
    int h = idx >> 7, jj = idx & 127, j4 = jj * 4;
    ushort4 ob;
    if (h < 12) {
      float4 p4 = *(const float4*)&logits[h][j4];
      float r = rinv[h];
      ob.x = f2b(p4.x * r); ob.y = f2b(p4.y * r);
      ob.z = f2b(p4.z * r); ob.w = f2b(p4.w * r);
    } else { ob.x = ob.y = ob.z = ob.w = 0; }
    int byte = (h * 1024 + j4 * 2) ^ ((h & 7) << 4);
    *(ushort4*)((char*)attnb + byte) = ob;
  }
  __syncthreads();

  size_t fb = (size_t)bi * 2112;

  // phase 5a: out_pair^T = zT @ p^T via MFMA; zT staged transposed in LDS (bf16, dbuf, 1 barrier/tile)
  {
    unsigned short* zts = (unsigned short*)&logits[0][0]; // 2 buffers x 5120 u16 (128 rows x 40)
    int jrow = tid >> 4;           // 0..31
    int c0s  = (tid & 15) << 3;    // 0,8,...,120
    const float* zsrc = zbase + jrow * 128 + c0s;
    int c0w = wv * 16;
    int crow = c0w + lr;
    f32x4 acc = {0.f, 0.f, 0.f, 0.f};

    float4 pa0 = *(const float4*)(zsrc);
    float4 pa1 = *(const float4*)(zsrc + 4);

    #pragma unroll 1
    for (int jt = 0; jt < 16; jt++) {
      unsigned short* buf = zts + (jt & 1) * 5120;
      float tmp[8] = {pa0.x, pa0.y, pa0.z, pa0.w, pa1.x, pa1.y, pa1.z, pa1.w};
      #pragma unroll
      for (int e = 0; e < 8; e++) {
        int c = c0s + e;
        buf[c * 40 + (jrow ^ ((c & 3) << 3))] = f2b(tmp[e]);
      }
      if (jt + 1 < 16) {
        pa0 = *(const float4*)(zsrc + (size_t)(jt + 1) * 32 * 128);
        pa1 = *(const float4*)(zsrc + (size_t)(jt + 1) * 32 * 128 + 4);
      }
      __syncthreads();
      bf16x8 afrag = *(const bf16x8*)(buf + crow * 40 + ((lk * 8) ^ ((crow & 3) << 3)));
      int abyte = (lr * 1024 + (jt * 32 + lk * 8) * 2) ^ ((lr & 7) << 4);
      bf16x8 pfrag = *(const bf16x8*)((const char*)attnb + abyte);
      acc = __builtin_amdgcn_mfma_f32_16x16x32_bf16(afrag, pfrag, acc, 0, 0, 0);
    }
    if (lr < 12) {
      ushort4 ow;
      ow.x = f2b(acc[0]); ow.y = f2b(acc[1]); ow.z = f2b(acc[2]); ow.w = f2b(acc[3]);
      *(ushort4*)&feats[fb + 576 + lr * 128 + c0w + lk * 4] = ow;
    }
  }

  // phase 5b: [out_scalar | rpg] = attn @ [v | vg] via MFMA over vT (L2-resident, contiguous 16B B-frags)
  {
    const unsigned short* vTb = vT + (size_t)b * 480 * 512;
    for (int t = wv; t < 30; t += 8) {
      int c0 = t * 16;
      const unsigned short* vrow = vTb + (size_t)(c0 + lr) * 512 + lk * 8;
      f32x4 acc = {0.f, 0.f, 0.f, 0.f};
      #pragma unroll
      for (int kc = 0; kc < 16; kc++) {
        bf16x8 bfrag = *(const bf16x8*)(vrow + kc * 32);
        int abyte = (lr * 1024 + (kc * 32 + lk * 8) * 2) ^ ((lr & 7) << 4);
        bf16x8 afrag = *(const bf16x8*)((const char*)attnb + abyte);
        acc = __builtin_amdgcn_mfma_f32_16x16x32_bf16(afrag, bfrag, acc, 0, 0, 0);
      }
      #pragma unroll
      for (int reg = 0; reg < 4; reg++) {
        int h = lk * 4 + reg;
        if (h < 12) {
          int c = c0 + lr;
          if (c < 192) { if ((c >> 4) == h) feats[fb + c] = f2b(acc[reg]); }
          else { int r = c - 192; if (r >= h * 24 && r < h * 24 + 24) rpg_lds[r] = acc[reg]; }
        }
      }
    }
  }
  __syncthreads();

  // phase 6: rpl = R^T (rpg - t), norms
  if (tid < 96) {
    int h = tid >> 3, pv = tid & 7;
    float gx = rpg_lds[h * 24 + pv * 3 + 0] - tl[0];
    float gy = rpg_lds[h * 24 + pv * 3 + 1] - tl[1];
    float gz = rpg_lds[h * 24 + pv * 3 + 2] - tl[2];
    float lx = Rl[0] * gx + Rl[3] * gy + Rl[6] * gz;
    float ly = Rl[1] * gx + Rl[4] * gy + Rl[7] * gz;
    float lz = Rl[2] * gx + Rl[5] * gy + Rl[8] * gz;
    feats[fb + 192 + tid] = f2b(lx);
    feats[fb + 288 + tid] = f2b(ly);
    feats[fb + 384 + tid] = f2b(lz);
    feats[fb + 480 + tid] = f2b(sqrtf(lx * lx + ly * ly + lz * lz + 1e-8f));
  }
}

// ---------------- K3: out = (feats @ wout + bout) * mask ----------------
__global__ __launch_bounds__(256) void k_out(const unsigned short* __restrict__ feats,
                                             const unsigned short* __restrict__ woutT,
                                             const float* __restrict__ bout,
                                             const float* __restrict__ mrow,
                                             float* __restrict__ out) {
  __shared__ unsigned short At[2048]; // [64 m][32 k] bf16 swizzled
  __shared__ unsigned short Bt[2048]; // [64 n][32 k] bf16 swizzled
  int m0 = blockIdx.x * 64, n0 = blockIdx.y * 64;
  int tid = threadIdx.x;
  int wv = tid >> 6, l = tid & 63, lr = l & 15, lk = l >> 4;
  int wm = wv >> 1, wn = wv & 1;
  f32x4 acc[2][2] = {};
  int sr = tid >> 2, sq = tid & 3;
  const char* fbase = (const char*)feats + (size_t)(m0 + sr) * 4224 + sq * 16;
  const char* bbase = (const char*)woutT + (size_t)(n0 + sr) * 4224 + sq * 16;
  int sw = ((sr * 64 + sq * 16) ^ ((sr & 7) << 4));

  uint4 av = *(const uint4*)(fbase);
  uint4 bv = *(const uint4*)(bbase);
  for (int k0 = 0; k0 < 2112; k0 += 32) {
    __syncthreads();
    *(uint4*)((char*)At + sw) = av;
    *(uint4*)((char*)Bt + sw) = bv;
    __syncthreads();
    if (k0 + 32 < 2112) {
      av = *(const uint4*)(fbase + (size_t)(k0 + 32) * 2);
      bv = *(const uint4*)(bbase + (size_t)(k0 + 32) * 2);
    }
    bf16x8 af[2], bf[2];
    #pragma unroll
    for (int mt = 0; mt < 2; mt++) {
      int row = wm * 32 + mt * 16 + lr;
      af[mt] = *(const bf16x8*)((const char*)At + ((row * 64 + lk * 16) ^ ((row & 7) << 4)));
    }
    #pragma unroll
    for (int nt = 0; nt < 2; nt++) {
      int row = wn * 32 + nt * 16 + lr;
      bf[nt] = *(const bf16x8*)((const char*)Bt + ((row * 64 + lk * 16) ^ ((row & 7) << 4)));
    }
    #pragma unroll
    for (int mt = 0; mt < 2; mt++)
      #pragma unroll
      for (int nt = 0; nt < 2; nt++)
        acc[mt][nt] = __builtin_amdgcn_mfma_f32_16x16x32_bf16(af[mt], bf[nt], acc[mt][nt], 0, 0, 0);
  }

  #pragma unroll
  for (int mt = 0; mt < 2; mt++) {
    #pragma unroll
    for (int nt = 0; nt < 2; nt++) {
      int nc = n0 + wn * 32 + nt * 16 + lr;
      float bo = bout[nc];
      #pragma unroll
      for (int reg = 0; reg < 4; reg++) {
        int rowg = m0 + wm * 32 + mt * 16 + lk * 4 + reg;
        out[(size_t)rowg * 384 + nc] = (acc[mt][nt][reg] + bo) * mrow[rowg];
      }
    }
  }
}

extern "C" void kernel_launch(void* const* d_in, const int* in_sizes, int n_in,
                              void* d_out, int out_size, void* d_ws, size_t ws_size,
                              hipStream_t stream) {
  const float* s    = (const float*)d_in[0];
  const float* z    = (const float*)d_in[1];
  const float* rot  = (const float*)d_in[2];
  const float* trn  = (const float*)d_in[3];
  const float* msk  = (const float*)d_in[4];
  const float* wq   = (const float*)d_in[5];
  const float* bq   = (const float*)d_in[6];
  const float* wkv  = (const float*)d_in[7];
  const float* bkv  = (const float*)d_in[8];
  const float* wqp  = (const float*)d_in[9];
  const float* bqp  = (const float*)d_in[10];
  const float* wkvp = (const float*)d_in[11];
  const float* bkvp = (const float*)d_in[12];
  const float* wb   = (const float*)d_in[13];
  const float* bb   = (const float*)d_in[14];
  const float* wout = (const float*)d_in[15];
  const float* bout = (const float*)d_in[16];
  const float* hwt  = (const float*)d_in[17];

  float* qws  = (float*)d_ws;                       // 196608 f32
  float* qgws = qws + 196608;                       // 147456 f32
  float* kT   = qgws + 147456;                      // 196608 f32
  float* kgT  = kT + 196608;                        // 147456 f32
  unsigned short* vT    = (unsigned short*)(kgT + 147456);  // 491520 u16
  unsigned short* feats = vT + 491520;              // 2162688 u16
  unsigned short* woutT = feats + 2162688;          // 811008 u16
  float* out = (float*)d_out;

  k_woutT<<<dim3(66, 12), dim3(256), 0, stream>>>(wout, woutT);
  k_proj<<<dim3(256), dim3(512), 0, stream>>>(s, wq, bq, wkv, bkv, wqp, bqp, wkvp, bkvp,
                                              rot, trn, qws, qgws, kT, kgT, vT);
  k_attn<<<dim3(1024), dim3(512), 0, stream>>>(z, msk, rot, trn, hwt, wb, bb,
                                               qws, qgws, kT, kgT, vT, feats);
  k_out<<<dim3(16, 6), dim3(256), 0, stream>>>(feats, woutT, bout, msk, out);
}